// Round 1
// baseline (290.842 us; speedup 1.0000x reference)
//
#include <hip/hip_runtime.h>

typedef __bf16 bf16;
typedef __bf16 bf16x8 __attribute__((ext_vector_type(8)));
typedef __bf16 bf16x4 __attribute__((ext_vector_type(4)));
typedef _Float16 f16x4 __attribute__((ext_vector_type(4)));
typedef _Float16 f16x8 __attribute__((ext_vector_type(8)));
typedef __fp16 h16x2 __attribute__((ext_vector_type(2)));
typedef float  f32x4  __attribute__((ext_vector_type(4)));
typedef float  f32x16 __attribute__((ext_vector_type(16)));
typedef unsigned int uint2v __attribute__((ext_vector_type(2)));
typedef unsigned int uint4v __attribute__((ext_vector_type(4)));

#define LOG2E 1.44269504088896340736f
#define SCQ (0.125f * LOG2E)

__device__ __forceinline__ void async16(const void* g, void* l) {
  __builtin_amdgcn_global_load_lds(
      (const __attribute__((address_space(1))) unsigned int*)g,
      (__attribute__((address_space(3))) unsigned int*)l, 16, 0, 0);
}

__device__ __forceinline__ f32x4 mfma_bf16(bf16x8 a, bf16x8 b, f32x4 c) {
  return __builtin_amdgcn_mfma_f32_16x16x32_bf16(a, b, c, 0, 0, 0);
}
__device__ __forceinline__ f32x16 mfma32_bf16(bf16x8 a, bf16x8 b, f32x16 c) {
  return __builtin_amdgcn_mfma_f32_32x32x16_bf16(a, b, c, 0, 0, 0);
}
__device__ __forceinline__ f32x16 mfma32x16_f16(f16x8 a, f16x8 b, f32x16 c) {
  return __builtin_amdgcn_mfma_f32_32x32x16_f16(a, b, c, 0, 0, 0);
}

// ------------- prep: fused activation cvt (fp32->bf16) + weight transpose -------
__global__ __launch_bounds__(256) void prep(const float* __restrict__ q,
                                            const float* __restrict__ k,
                                            const float* __restrict__ v,
                                            const float* __restrict__ W0,
                                            const float* __restrict__ W1,
                                            const float* __restrict__ W2,
                                            bf16* __restrict__ actb,
                                            bf16* __restrict__ Wt) {
  __shared__ float t[64 * 69];
  const int z = blockIdx.y, tid = threadIdx.x;
  if (blockIdx.x < 4096) {
    const float* in = z == 0 ? q : (z == 1 ? k : v);
    bf16* o = actb + (size_t)z * 8388608;
    int i = blockIdx.x * 256 + tid;
    const float4* p = (const float4*)in;
    float4 a = p[i * 2], c = p[i * 2 + 1];
    bf16x8 r;
    r[0] = (bf16)a.x; r[1] = (bf16)a.y; r[2] = (bf16)a.z; r[3] = (bf16)a.w;
    r[4] = (bf16)c.x; r[5] = (bf16)c.y; r[6] = (bf16)c.z; r[7] = (bf16)c.w;
    ((bf16x8*)o)[i] = r;
  } else {
    const float* W = z == 0 ? W0 : (z == 1 ? W1 : W2);
    bf16* O = Wt + (size_t)z * (1024 * 1024);
    int lin = blockIdx.x - 4096;
    int k0 = (lin & 15) * 64, n0 = (lin >> 4) * 64;
    int r0 = tid >> 4, c0 = (tid & 15) * 4;
#pragma unroll
    for (int rr = 0; rr < 4; rr++) {
      int kk = r0 + rr * 16;
      float4 vv = *(const float4*)(W + (k0 + kk) * 1024 + n0 + c0);
      t[kk * 69 + c0 + 0] = vv.x; t[kk * 69 + c0 + 1] = vv.y;
      t[kk * 69 + c0 + 2] = vv.z; t[kk * 69 + c0 + 3] = vv.w;
    }
    __syncthreads();
#pragma unroll
    for (int rr = 0; rr < 4; rr++) {
      int n = r0 + rr * 16;
      bf16x4 o;
#pragma unroll
      for (int j = 0; j < 4; j++) o[j] = (bf16)t[(c0 + j) * 69 + n];
      *(bf16x4*)(O + (n0 + n) * 1024 + k0 + c0) = o;
    }
  }
}

// ---------------- batched projection GEMM, 128x128, m97 config ----------------
// z=0: qo = (A*Wq+bq)*SCQ bf16 [m][n]; z=1: ko = A*Wk+bk bf16 [m][n];
// z=2: vf = A*Wv+bv f16, 32x32x16-A-fragment order:
//      element (kv,d) of head hh: t32=(kv>>5)&3, u16=(kv>>4)&1, hl=(kv>>3)&1,
//      j=kv&7; db=(d>>5)&1; fi=(t32*2+u16)*2+db; lane=32*hl+(d&31);
//      off = (((b*16+hh)*16+kvb)*16+fi)*512 + lane*8 + j
__global__ __launch_bounds__(256, 3) void gemm_qkv(const bf16* __restrict__ Act,
                                                   const bf16* __restrict__ Wt,
                                                   const float* __restrict__ b0,
                                                   const float* __restrict__ b1,
                                                   const float* __restrict__ b2,
                                                   bf16* __restrict__ qo,
                                                   bf16* __restrict__ ko,
                                                   _Float16* __restrict__ vf) {
  __shared__ bf16 smem[16384];          // sA 8192 | sB 8192 (32 KB)
  bf16* sA = smem;
  bf16* sB = smem + 8192;
  const int tid = threadIdx.x;
  const int wave = tid >> 6, lane = tid & 63;
  const int quad = lane >> 4, l15 = lane & 15;
  const int z = blockIdx.z;
  const int m0 = blockIdx.x * 128, n0 = blockIdx.y * 128;
  const bf16* A = Act + (size_t)z * 8388608;
  const bf16* Bt = Wt + (size_t)z * 1048576;
  const float* bias = z == 0 ? b0 : (z == 1 ? b1 : b2);

  const bf16* ap[4]; const bf16* bp[4]; int lo[4];
#pragma unroll
  for (int i = 0; i < 4; i++) {
    int g = wave * 256 + i * 64 + lane;
    int row = g >> 3, jl = (g & 7) ^ (row & 7);
    ap[i] = A + (m0 + row) * 1024 + jl * 8;
    bp[i] = Bt + (n0 + row) * 1024 + jl * 8;
    lo[i] = (wave * 256 + i * 64) * 8;
  }
  const int wm = (wave & 1) * 64, wn = (wave >> 1) * 64;
  f32x4 acc[4][4] = {};

  for (int kt = 0; kt < 16; kt++) {
    const int ko_ = kt * 64;
#pragma unroll
    for (int i = 0; i < 4; i++) async16(ap[i] + ko_, sA + lo[i]);
#pragma unroll
    for (int i = 0; i < 4; i++) async16(bp[i] + ko_, sB + lo[i]);
    __syncthreads();
#pragma unroll
    for (int ks = 0; ks < 2; ks++) {
      bf16x8 af[4], bv[4];
#pragma unroll
      for (int mt = 0; mt < 4; mt++) {
        int m = wm + mt * 16 + l15;
        int ph = (ks * 4 + quad) ^ (m & 7);
        af[mt] = *(const bf16x8*)(sA + m * 64 + ph * 8);
      }
#pragma unroll
      for (int nt = 0; nt < 4; nt++) {
        int n = wn + nt * 16 + l15;
        int ph = (ks * 4 + quad) ^ (n & 7);
        bv[nt] = *(const bf16x8*)(sB + n * 64 + ph * 8);
      }
#pragma unroll
      for (int mt = 0; mt < 4; mt++)
#pragma unroll
        for (int nt = 0; nt < 4; nt++)
          acc[mt][nt] = mfma_bf16(af[mt], bv[nt], acc[mt][nt]);
    }
    __syncthreads();
  }

  if (z != 2) {
    bf16* O = z == 0 ? qo : ko;
    const float sc = z == 0 ? SCQ : 1.0f;
#pragma unroll
    for (int nt = 0; nt < 4; nt++) {
      int n = n0 + wn + nt * 16 + l15;
      float bc = bias[n];
#pragma unroll
      for (int mt = 0; mt < 4; mt++)
#pragma unroll
        for (int r = 0; r < 4; r++) {
          int m = m0 + wm + mt * 16 + quad * 4 + r;
          O[m * 1024 + n] = (bf16)((acc[mt][nt][r] + bc) * sc);
        }
    }
  } else {
    // 32x32x16 A-fragment-order stores (see header comment)
    // kv = m0 + wm + mt*16 + quad*4 + r:
    //   j = kv&7 = (quad&1)*4 + r ; hl = (kv>>3)&1 = quad>>1 ;
    //   u16 = mt&1 ; t32 = 2*(wave&1) + (mt>>1)
    //   fi = (t32*2+u16)*2+db = ((wave&1)*4 + mt)*2 + db  (same as before)
    const int b = m0 >> 11, s0 = m0 & 2047;
    const int kvb = s0 >> 7;
    const int mtg0 = (wave & 1) * 4;
    const int hl = quad >> 1, jb = (quad & 1) * 4;
#pragma unroll
    for (int nt = 0; nt < 4; nt++) {
      int n = n0 + wn + nt * 16;
      int hh = n >> 6, db = (n >> 5) & 1;
      int lanep = hl * 32 + (n & 31) + l15;
      float bc = bias[n + l15];
#pragma unroll
      for (int mt = 0; mt < 4; mt++) {
        int fi = (mtg0 + mt) * 2 + db;
        f16x4 pk;
#pragma unroll
        for (int r = 0; r < 4; r++) pk[r] = (_Float16)(acc[mt][nt][r] + bc);
        size_t off = ((((size_t)(b * 16 + hh) * 16 + kvb) * 16 + fi) * 512)
                     + lanep * 8 + jb;
        *(f16x4*)(vf + off) = pk;
      }
    }
  }
}

// ------------- flash attention, 32x32 core, KV-128 single-buffer ------------
// Q pre-scaled bf16 [B,S,1024]; K bf16 [B,S,1024]; VF f16 32x32x16-frag order;
// Out fp32 [B,S,1024]. Q-tile 128 (wave owns 32 q rows). 48 KB LDS.
// S^T = K·Q^T via mfma_32x32x16_bf16; its C-layout rows kv=(reg&3)+8(reg>>2)+4hl
// are re-paired across lane halves with v_permlane32_swap_b32 into the
// B-operand layout (kv = 8*hl + j) of mfma_32x32x16_f16 — full-rate PV.
__global__ __launch_bounds__(256, 3) void attn(const bf16* __restrict__ Q,
                                               const bf16* __restrict__ K,
                                               const _Float16* __restrict__ VF,
                                               float* __restrict__ Out) {
  __shared__ bf16 sQ[8192];        // 128 x 64 swizzled (16 KB)
  __shared__ bf16 sK[8192];        // 128 x 64 swizzled (16 KB)
  __shared__ _Float16 sV[8192];    // 16 frags x 64 lanes x 8 (16 KB)
  const int tid = threadIdx.x;
  const int wave = tid >> 6, lane = tid & 63;
  const int l31 = lane & 31, hl = lane >> 5;
  const int q0 = blockIdx.x * 128, hh = blockIdx.y, b = blockIdx.z;
  const bf16* Kbase = K + (size_t)(b * 2048) * 1024 + hh * 64;
  const _Float16* Vbase = VF + (size_t)(b * 16 + hh) * 131072;

  // stage Q + K/V block 0
#pragma unroll
  for (int i = 0; i < 4; i++) {
    int g = i * 256 + tid;
    int row = g >> 3, jl = (g & 7) ^ (row & 7);
    async16(Q + (size_t)(b * 2048 + q0 + row) * 1024 + hh * 64 + jl * 8, sQ + g * 8);
    async16(Kbase + (size_t)row * 1024 + jl * 8, sK + g * 8);
    async16(Vbase + g * 8, sV + g * 8);
  }
  __syncthreads();

  // Q fragments (B-operand of 32x32x16: n=q=lane&31, k=d=16i+8*hl+j)
  bf16x8 qf[4];
  {
    int rowq = wave * 32 + l31, rx = rowq & 7;
#pragma unroll
    for (int i = 0; i < 4; i++)
      qf[i] = *(const bf16x8*)(sQ + rowq * 64 + ((2 * i + hl) ^ rx) * 8);
  }

  f32x16 oacc[2] = {};    // O^T: [db] rows d = 32db + (reg&3)+8(reg>>2)+4hl, col q
  float ls = 0.f;

  for (int kvb = 0; kvb < 16; kvb++) {
#pragma unroll
    for (int t32 = 0; t32 < 4; t32++) {
      // ---- S^T (32 kv x 32 q): A=K rows kv, B=Q^T ----
      int rowk = t32 * 32 + l31, rx = rowk & 7;
      const bf16* kr = sK + rowk * 64;
      f32x16 st = {};
#pragma unroll
      for (int i = 0; i < 4; i++) {
        bf16x8 kf = *(const bf16x8*)(kr + ((2 * i + hl) ^ rx) * 8);
        st = mfma32_bf16(kf, qf[i], st);
      }
      // ---- exp2 + pack to f16 dword pairs ----
      // dw[2s+p] holds kv (8s+4*hl+2p, +1) for column q=l31
      unsigned int dw[8];
      float ps = 0.f;
#pragma unroll
      for (int s = 0; s < 4; s++) {
        float p0 = __builtin_amdgcn_exp2f(st[4 * s + 0]);
        float p1 = __builtin_amdgcn_exp2f(st[4 * s + 1]);
        float p2 = __builtin_amdgcn_exp2f(st[4 * s + 2]);
        float p3 = __builtin_amdgcn_exp2f(st[4 * s + 3]);
        ps += (p0 + p1) + (p2 + p3);
        dw[2 * s]     = __builtin_bit_cast(unsigned int,
                          __builtin_amdgcn_cvt_pkrtz(p0, p1));
        dw[2 * s + 1] = __builtin_bit_cast(unsigned int,
                          __builtin_amdgcn_cvt_pkrtz(p2, p3));
      }
      ls += ps;
      // ---- O^T += V^T P^T : permlane-swap P into K=16 B-frags, 4 mfma ----
      // swap(low-group dw, high-group dw): r[0]={lo:own-lo, hi:partner-lo},
      // r[1]={lo:partner-hi, hi:own-hi} -> frag dwords j01/j23 and j45/j67.
#pragma unroll
      for (int u = 0; u < 2; u++) {
        uint2v rA = __builtin_amdgcn_permlane32_swap(dw[4 * u + 0],
                                                     dw[4 * u + 2], false, false);
        uint2v rB = __builtin_amdgcn_permlane32_swap(dw[4 * u + 1],
                                                     dw[4 * u + 3], false, false);
        uint4v uu;
        uu[0] = rA[0]; uu[1] = rB[0]; uu[2] = rA[1]; uu[3] = rB[1];
        f16x8 pfrag = __builtin_bit_cast(f16x8, uu);
#pragma unroll
        for (int db = 0; db < 2; db++) {
          f16x8 va = *(const f16x8*)(sV + ((t32 * 4 + u * 2 + db) * 64 + lane) * 8);
          oacc[db] = mfma32x16_f16(va, pfrag, oacc[db]);
        }
      }
    }
    __syncthreads();
    if (kvb < 15) {
      int kn = (kvb + 1) * 128;
#pragma unroll
      for (int i = 0; i < 4; i++) {
        int g = i * 256 + tid;
        int row = g >> 3, jl = (g & 7) ^ (row & 7);
        async16(Kbase + (size_t)(kn + row) * 1024 + jl * 8, sK + g * 8);
        async16(Vbase + (kvb + 1) * 8192 + g * 8, sV + g * 8);
      }
      __syncthreads();
    }
  }

  // ---- epilogue: l = own-half + other-half, scale, store fp32 ----
  ls += __shfl_xor(ls, 32);
  float inv = 1.f / ls;
  int qrow = b * 2048 + q0 + wave * 32 + l31;
  float* orow = Out + (size_t)qrow * 1024 + hh * 64;
#pragma unroll
  for (int db = 0; db < 2; db++)
#pragma unroll
    for (int rg = 0; rg < 4; rg++) {
      float4 v;
      v.x = oacc[db][4 * rg + 0] * inv;
      v.y = oacc[db][4 * rg + 1] * inv;
      v.z = oacc[db][4 * rg + 2] * inv;
      v.w = oacc[db][4 * rg + 3] * inv;
      *(float4*)(orow + db * 32 + rg * 8 + 4 * hl) = v;
    }
}

extern "C" void kernel_launch(void* const* d_in, const int* in_sizes, int n_in,
                              void* d_out, int out_size, void* d_ws, size_t ws_size,
                              hipStream_t stream) {
  const float* key   = (const float*)d_in[0];
  const float* value = (const float*)d_in[1];
  const float* query = (const float*)d_in[2];
  const float* Wq = (const float*)d_in[3];
  const float* bq = (const float*)d_in[4];
  const float* Wk = (const float*)d_in[5];
  const float* bk = (const float*)d_in[6];
  const float* Wv = (const float*)d_in[7];
  const float* bv = (const float*)d_in[8];
  float* out = (float*)d_out;

  char* ws = (char*)d_ws;
  bf16* actb   = (bf16*)(ws);                       // 48 MB: [query|key|value] bf16
  bf16* wt     = (bf16*)(ws + 50331648);            // 6 MB: Wq^T,Wk^T,Wv^T
  bf16* qo     = (bf16*)(ws + 56623104);            // 16 MB (pre-scaled)
  bf16* ko     = (bf16*)(ws + 73400320);            // 16 MB
  _Float16* vf = (_Float16*)(ws + 90177536);        // 16 MB 32x32x16-frag order
  (void)in_sizes; (void)n_in; (void)out_size; (void)ws_size;

  prep<<<dim3(4352, 3), 256, 0, stream>>>(query, key, value, Wq, Wk, Wv, actb, wt);
  gemm_qkv<<<dim3(64, 8, 3), 256, 0, stream>>>(actb, wt, bq, bk, bv, qo, ko, vf);
  attn<<<dim3(16, 16, 4), 256, 0, stream>>>(qo, ko, vf, out);
}

// Round 2
// 290.041 us; speedup vs baseline: 1.0028x; 1.0028x over previous
//
#include <hip/hip_runtime.h>

typedef __bf16 bf16;
typedef __bf16 bf16x8 __attribute__((ext_vector_type(8)));
typedef __bf16 bf16x4 __attribute__((ext_vector_type(4)));
typedef _Float16 f16x4 __attribute__((ext_vector_type(4)));
typedef _Float16 f16x8 __attribute__((ext_vector_type(8)));
typedef __fp16 h16x2 __attribute__((ext_vector_type(2)));
typedef float  f32x4  __attribute__((ext_vector_type(4)));
typedef float  f32x16 __attribute__((ext_vector_type(16)));
typedef unsigned int uint2v __attribute__((ext_vector_type(2)));
typedef unsigned int uint4v __attribute__((ext_vector_type(4)));

#define LOG2E 1.44269504088896340736f
#define SCQ (0.125f * LOG2E)

__device__ __forceinline__ void async16(const void* g, void* l) {
  __builtin_amdgcn_global_load_lds(
      (const __attribute__((address_space(1))) unsigned int*)g,
      (__attribute__((address_space(3))) unsigned int*)l, 16, 0, 0);
}

__device__ __forceinline__ f32x4 mfma_bf16(bf16x8 a, bf16x8 b, f32x4 c) {
  return __builtin_amdgcn_mfma_f32_16x16x32_bf16(a, b, c, 0, 0, 0);
}
__device__ __forceinline__ f32x16 mfma32_bf16(bf16x8 a, bf16x8 b, f32x16 c) {
  return __builtin_amdgcn_mfma_f32_32x32x16_bf16(a, b, c, 0, 0, 0);
}
__device__ __forceinline__ f32x16 mfma32x16_f16(f16x8 a, f16x8 b, f32x16 c) {
  return __builtin_amdgcn_mfma_f32_32x32x16_f16(a, b, c, 0, 0, 0);
}

// ------------- prep: fused activation cvt (fp32->bf16) + weight transpose -------
__global__ __launch_bounds__(256) void prep(const float* __restrict__ q,
                                            const float* __restrict__ k,
                                            const float* __restrict__ v,
                                            const float* __restrict__ W0,
                                            const float* __restrict__ W1,
                                            const float* __restrict__ W2,
                                            bf16* __restrict__ actb,
                                            bf16* __restrict__ Wt) {
  __shared__ float t[64 * 69];
  const int z = blockIdx.y, tid = threadIdx.x;
  if (blockIdx.x < 4096) {
    const float* in = z == 0 ? q : (z == 1 ? k : v);
    bf16* o = actb + (size_t)z * 8388608;
    int i = blockIdx.x * 256 + tid;
    const float4* p = (const float4*)in;
    float4 a = p[i * 2], c = p[i * 2 + 1];
    bf16x8 r;
    r[0] = (bf16)a.x; r[1] = (bf16)a.y; r[2] = (bf16)a.z; r[3] = (bf16)a.w;
    r[4] = (bf16)c.x; r[5] = (bf16)c.y; r[6] = (bf16)c.z; r[7] = (bf16)c.w;
    ((bf16x8*)o)[i] = r;
  } else {
    const float* W = z == 0 ? W0 : (z == 1 ? W1 : W2);
    bf16* O = Wt + (size_t)z * (1024 * 1024);
    int lin = blockIdx.x - 4096;
    int k0 = (lin & 15) * 64, n0 = (lin >> 4) * 64;
    int r0 = tid >> 4, c0 = (tid & 15) * 4;
#pragma unroll
    for (int rr = 0; rr < 4; rr++) {
      int kk = r0 + rr * 16;
      float4 vv = *(const float4*)(W + (k0 + kk) * 1024 + n0 + c0);
      t[kk * 69 + c0 + 0] = vv.x; t[kk * 69 + c0 + 1] = vv.y;
      t[kk * 69 + c0 + 2] = vv.z; t[kk * 69 + c0 + 3] = vv.w;
    }
    __syncthreads();
#pragma unroll
    for (int rr = 0; rr < 4; rr++) {
      int n = r0 + rr * 16;
      bf16x4 o;
#pragma unroll
      for (int j = 0; j < 4; j++) o[j] = (bf16)t[(c0 + j) * 69 + n];
      *(bf16x4*)(O + (n0 + n) * 1024 + k0 + c0) = o;
    }
  }
}

// ---------------- batched projection GEMM, 128x128, m97 config ----------------
// z=0: qo = (A*Wq+bq)*SCQ bf16 [m][n]; z=1: ko = A*Wk+bk bf16 [m][n];
// z=2: vf = A*Wv+bv f16, 32x32x16-A-fragment order:
//      element (kv,d) of head hh: t32=(kv>>5)&3, u16=(kv>>4)&1, hl=(kv>>3)&1,
//      j=kv&7; db=(d>>5)&1; fi=(t32*2+u16)*2+db; lane=32*hl+(d&31);
//      off = (((b*16+hh)*16+kvb)*16+fi)*512 + lane*8 + j
__global__ __launch_bounds__(256, 3) void gemm_qkv(const bf16* __restrict__ Act,
                                                   const bf16* __restrict__ Wt,
                                                   const float* __restrict__ b0,
                                                   const float* __restrict__ b1,
                                                   const float* __restrict__ b2,
                                                   bf16* __restrict__ qo,
                                                   bf16* __restrict__ ko,
                                                   _Float16* __restrict__ vf) {
  __shared__ bf16 smem[16384];          // sA 8192 | sB 8192 (32 KB)
  bf16* sA = smem;
  bf16* sB = smem + 8192;
  const int tid = threadIdx.x;
  const int wave = tid >> 6, lane = tid & 63;
  const int quad = lane >> 4, l15 = lane & 15;
  const int z = blockIdx.z;
  const int m0 = blockIdx.x * 128, n0 = blockIdx.y * 128;
  const bf16* A = Act + (size_t)z * 8388608;
  const bf16* Bt = Wt + (size_t)z * 1048576;
  const float* bias = z == 0 ? b0 : (z == 1 ? b1 : b2);

  const bf16* ap[4]; const bf16* bp[4]; int lo[4];
#pragma unroll
  for (int i = 0; i < 4; i++) {
    int g = wave * 256 + i * 64 + lane;
    int row = g >> 3, jl = (g & 7) ^ (row & 7);
    ap[i] = A + (m0 + row) * 1024 + jl * 8;
    bp[i] = Bt + (n0 + row) * 1024 + jl * 8;
    lo[i] = (wave * 256 + i * 64) * 8;
  }
  const int wm = (wave & 1) * 64, wn = (wave >> 1) * 64;
  f32x4 acc[4][4] = {};

  for (int kt = 0; kt < 16; kt++) {
    const int ko_ = kt * 64;
#pragma unroll
    for (int i = 0; i < 4; i++) async16(ap[i] + ko_, sA + lo[i]);
#pragma unroll
    for (int i = 0; i < 4; i++) async16(bp[i] + ko_, sB + lo[i]);
    __syncthreads();
#pragma unroll
    for (int ks = 0; ks < 2; ks++) {
      bf16x8 af[4], bv[4];
#pragma unroll
      for (int mt = 0; mt < 4; mt++) {
        int m = wm + mt * 16 + l15;
        int ph = (ks * 4 + quad) ^ (m & 7);
        af[mt] = *(const bf16x8*)(sA + m * 64 + ph * 8);
      }
#pragma unroll
      for (int nt = 0; nt < 4; nt++) {
        int n = wn + nt * 16 + l15;
        int ph = (ks * 4 + quad) ^ (n & 7);
        bv[nt] = *(const bf16x8*)(sB + n * 64 + ph * 8);
      }
#pragma unroll
      for (int mt = 0; mt < 4; mt++)
#pragma unroll
        for (int nt = 0; nt < 4; nt++)
          acc[mt][nt] = mfma_bf16(af[mt], bv[nt], acc[mt][nt]);
    }
    __syncthreads();
  }

  if (z != 2) {
    bf16* O = z == 0 ? qo : ko;
    const float sc = z == 0 ? SCQ : 1.0f;
#pragma unroll
    for (int nt = 0; nt < 4; nt++) {
      int n = n0 + wn + nt * 16 + l15;
      float bc = bias[n];
#pragma unroll
      for (int mt = 0; mt < 4; mt++)
#pragma unroll
        for (int r = 0; r < 4; r++) {
          int m = m0 + wm + mt * 16 + quad * 4 + r;
          O[m * 1024 + n] = (bf16)((acc[mt][nt][r] + bc) * sc);
        }
    }
  } else {
    // 32x32x16 A-fragment-order stores (see header comment)
    // kv = m0 + wm + mt*16 + quad*4 + r:
    //   j = kv&7 = (quad&1)*4 + r ; hl = (kv>>3)&1 = quad>>1 ;
    //   u16 = mt&1 ; t32 = 2*(wave&1) + (mt>>1)
    //   fi = (t32*2+u16)*2+db = ((wave&1)*4 + mt)*2 + db
    const int b = m0 >> 11, s0 = m0 & 2047;
    const int kvb = s0 >> 7;
    const int mtg0 = (wave & 1) * 4;
    const int hl = quad >> 1, jb = (quad & 1) * 4;
#pragma unroll
    for (int nt = 0; nt < 4; nt++) {
      int n = n0 + wn + nt * 16;
      int hh = n >> 6, db = (n >> 5) & 1;
      int lanep = hl * 32 + (n & 31) + l15;
      float bc = bias[n + l15];
#pragma unroll
      for (int mt = 0; mt < 4; mt++) {
        int fi = (mtg0 + mt) * 2 + db;
        f16x4 pk;
#pragma unroll
        for (int r = 0; r < 4; r++) pk[r] = (_Float16)(acc[mt][nt][r] + bc);
        size_t off = ((((size_t)(b * 16 + hh) * 16 + kvb) * 16 + fi) * 512)
                     + lanep * 8 + jb;
        *(f16x4*)(vf + off) = pk;
      }
    }
  }
}

// ------------- flash attention, 32x32 core, KV-64 DOUBLE-buffered ------------
// Q pre-scaled bf16 [B,S,1024]; K bf16 [B,S,1024]; VF f16 32x32x16-frag order;
// Out fp32 [B,S,1024]. Q-tile 128 (wave owns 32 q rows). 48 KB LDS, 3 blk/CU.
// 2-phase pipeline: stage(t+1, buf^1) issued BEFORE compute(buf); single
// barrier per iteration (its implicit vmcnt(0) lands AFTER compute, so the
// global_load_lds latency hides under MFMA+exp2).
__global__ __launch_bounds__(256, 3) void attn(const bf16* __restrict__ Q,
                                               const bf16* __restrict__ K,
                                               const _Float16* __restrict__ VF,
                                               float* __restrict__ Out) {
  __shared__ bf16 sQ[8192];                 // 128 x 64 swizzled (16 KB)
  __shared__ bf16 sK0[4096], sK1[4096];     // 64 x 64 swizzled, dbuf (2x8 KB)
  __shared__ _Float16 sV0[4096], sV1[4096]; // 8 frags x 64 x 8, dbuf (2x8 KB)
  const int tid = threadIdx.x;
  const int wave = tid >> 6, lane = tid & 63;
  const int l31 = lane & 31, hl = lane >> 5;
  const int q0 = blockIdx.x * 128, hh = blockIdx.y, b = blockIdx.z;
  const bf16* Kbase = K + (size_t)(b * 2048) * 1024 + hh * 64;
  const _Float16* Vbase = VF + (size_t)(b * 16 + hh) * 131072;

  // per-thread staging addresses (2 K-loads + 2 V-loads per 64-row block)
  const int g0 = tid, g1 = 256 + tid;
  const int r0s = g0 >> 3, j0s = (g0 & 7) ^ (r0s & 7);
  const int r1s = g1 >> 3, j1s = (g1 & 7) ^ (r1s & 7);
  const bf16* kst0 = Kbase + (size_t)r0s * 1024 + j0s * 8;
  const bf16* kst1 = Kbase + (size_t)r1s * 1024 + j1s * 8;

  auto stageKV = [&](int t, bf16* sk, _Float16* sv) {
    async16(kst0 + (size_t)t * 65536, sk + g0 * 8);
    async16(kst1 + (size_t)t * 65536, sk + g1 * 8);
    async16(Vbase + t * 4096 + g0 * 8, sv + g0 * 8);
    async16(Vbase + t * 4096 + g1 * 8, sv + g1 * 8);
  };

  // prologue: Q (16 KB) + K/V block 0
#pragma unroll
  for (int i = 0; i < 4; i++) {
    int g = i * 256 + tid;
    int row = g >> 3, jl = (g & 7) ^ (row & 7);
    async16(Q + (size_t)(b * 2048 + q0 + row) * 1024 + hh * 64 + jl * 8, sQ + g * 8);
  }
  stageKV(0, sK0, sV0);
  __syncthreads();

  // Q fragments (B-operand of 32x32x16: n=q=lane&31, k=d=16i+8*hl+j)
  bf16x8 qf[4];
  {
    int rowq = wave * 32 + l31, rx = rowq & 7;
#pragma unroll
    for (int i = 0; i < 4; i++)
      qf[i] = *(const bf16x8*)(sQ + rowq * 64 + ((2 * i + hl) ^ rx) * 8);
  }

  f32x16 oacc[2] = {};    // O^T: [db] rows d = 32db + (reg&3)+8(reg>>2)+4hl, col q
  float ls = 0.f;

  auto computeT = [&](const bf16* sk, const _Float16* sv) {
#pragma unroll
    for (int t32 = 0; t32 < 2; t32++) {
      // ---- S^T (32 kv x 32 q): A=K rows kv, B=Q^T ----
      int rowk = t32 * 32 + l31, rx = rowk & 7;
      const bf16* kr = sk + rowk * 64;
      f32x16 st = {};
#pragma unroll
      for (int i = 0; i < 4; i++) {
        bf16x8 kf = *(const bf16x8*)(kr + ((2 * i + hl) ^ rx) * 8);
        st = mfma32_bf16(kf, qf[i], st);
      }
      // ---- exp2 + pack to f16 dword pairs ----
      unsigned int dw[8];
      float ps = 0.f;
#pragma unroll
      for (int s = 0; s < 4; s++) {
        float p0 = __builtin_amdgcn_exp2f(st[4 * s + 0]);
        float p1 = __builtin_amdgcn_exp2f(st[4 * s + 1]);
        float p2 = __builtin_amdgcn_exp2f(st[4 * s + 2]);
        float p3 = __builtin_amdgcn_exp2f(st[4 * s + 3]);
        ps += (p0 + p1) + (p2 + p3);
        dw[2 * s]     = __builtin_bit_cast(unsigned int,
                          __builtin_amdgcn_cvt_pkrtz(p0, p1));
        dw[2 * s + 1] = __builtin_bit_cast(unsigned int,
                          __builtin_amdgcn_cvt_pkrtz(p2, p3));
      }
      ls += ps;
      // ---- O^T += V^T P^T : permlane-swap into K=16 B-frags, 4 mfma ----
#pragma unroll
      for (int u = 0; u < 2; u++) {
        uint2v rA = __builtin_amdgcn_permlane32_swap(dw[4 * u + 0],
                                                     dw[4 * u + 2], false, false);
        uint2v rB = __builtin_amdgcn_permlane32_swap(dw[4 * u + 1],
                                                     dw[4 * u + 3], false, false);
        uint4v uu;
        uu[0] = rA[0]; uu[1] = rB[0]; uu[2] = rA[1]; uu[3] = rB[1];
        f16x8 pfrag = __builtin_bit_cast(f16x8, uu);
#pragma unroll
        for (int db = 0; db < 2; db++) {
          f16x8 va = *(const f16x8*)(sv + ((t32 * 4 + u * 2 + db) * 64 + lane) * 8);
          oacc[db] = mfma32x16_f16(va, pfrag, oacc[db]);
        }
      }
    }
  };

  // 2-phase main loop over 32 KV-64 blocks (statically named buffers)
#pragma unroll 1
  for (int t = 0; t < 32; t += 2) {
    stageKV(t + 1, sK1, sV1);      // loads fly under compute
    computeT(sK0, sV0);
    __syncthreads();               // drains stage(t+1); buf0 readers done
    if (t + 2 < 32) stageKV(t + 2, sK0, sV0);
    computeT(sK1, sV1);
    __syncthreads();
  }

  // ---- epilogue: l = own-half + other-half, scale, store fp32 ----
  ls += __shfl_xor(ls, 32);
  float inv = 1.f / ls;
  int qrow = b * 2048 + q0 + wave * 32 + l31;
  float* orow = Out + (size_t)qrow * 1024 + hh * 64;
#pragma unroll
  for (int db = 0; db < 2; db++)
#pragma unroll
    for (int rg = 0; rg < 4; rg++) {
      float4 v;
      v.x = oacc[db][4 * rg + 0] * inv;
      v.y = oacc[db][4 * rg + 1] * inv;
      v.z = oacc[db][4 * rg + 2] * inv;
      v.w = oacc[db][4 * rg + 3] * inv;
      *(float4*)(orow + db * 32 + rg * 8 + 4 * hl) = v;
    }
}

extern "C" void kernel_launch(void* const* d_in, const int* in_sizes, int n_in,
                              void* d_out, int out_size, void* d_ws, size_t ws_size,
                              hipStream_t stream) {
  const float* key   = (const float*)d_in[0];
  const float* value = (const float*)d_in[1];
  const float* query = (const float*)d_in[2];
  const float* Wq = (const float*)d_in[3];
  const float* bq = (const float*)d_in[4];
  const float* Wk = (const float*)d_in[5];
  const float* bk = (const float*)d_in[6];
  const float* Wv = (const float*)d_in[7];
  const float* bv = (const float*)d_in[8];
  float* out = (float*)d_out;

  char* ws = (char*)d_ws;
  bf16* actb   = (bf16*)(ws);                       // 48 MB: [query|key|value] bf16
  bf16* wt     = (bf16*)(ws + 50331648);            // 6 MB: Wq^T,Wk^T,Wv^T
  bf16* qo     = (bf16*)(ws + 56623104);            // 16 MB (pre-scaled)
  bf16* ko     = (bf16*)(ws + 73400320);            // 16 MB
  _Float16* vf = (_Float16*)(ws + 90177536);        // 16 MB 32x32x16-frag order
  (void)in_sizes; (void)n_in; (void)out_size; (void)ws_size;

  prep<<<dim3(4352, 3), 256, 0, stream>>>(query, key, value, Wq, Wk, Wv, actb, wt);
  gemm_qkv<<<dim3(64, 8, 3), 256, 0, stream>>>(actb, wt, bq, bk, bv, qo, ko, vf);
  attn<<<dim3(16, 16, 4), 256, 0, stream>>>(qo, ko, vf, out);
}

// Round 3
// 289.675 us; speedup vs baseline: 1.0040x; 1.0013x over previous
//
#include <hip/hip_runtime.h>

typedef __bf16 bf16;
typedef __bf16 bf16x8 __attribute__((ext_vector_type(8)));
typedef __bf16 bf16x4 __attribute__((ext_vector_type(4)));
typedef _Float16 f16x4 __attribute__((ext_vector_type(4)));
typedef _Float16 f16x8 __attribute__((ext_vector_type(8)));
typedef __fp16 h16x2 __attribute__((ext_vector_type(2)));
typedef float  f32x4  __attribute__((ext_vector_type(4)));
typedef float  f32x16 __attribute__((ext_vector_type(16)));
typedef unsigned int uint2v __attribute__((ext_vector_type(2)));
typedef unsigned int uint4v __attribute__((ext_vector_type(4)));

#define LOG2E 1.44269504088896340736f
#define SCQ (0.125f * LOG2E)

__device__ __forceinline__ void async16(const void* g, void* l) {
  __builtin_amdgcn_global_load_lds(
      (const __attribute__((address_space(1))) unsigned int*)g,
      (__attribute__((address_space(3))) unsigned int*)l, 16, 0, 0);
}

__device__ __forceinline__ f32x4 mfma_bf16(bf16x8 a, bf16x8 b, f32x4 c) {
  return __builtin_amdgcn_mfma_f32_16x16x32_bf16(a, b, c, 0, 0, 0);
}
__device__ __forceinline__ f32x16 mfma32_bf16(bf16x8 a, bf16x8 b, f32x16 c) {
  return __builtin_amdgcn_mfma_f32_32x32x16_bf16(a, b, c, 0, 0, 0);
}
__device__ __forceinline__ f32x16 mfma32x16_f16(f16x8 a, f16x8 b, f32x16 c) {
  return __builtin_amdgcn_mfma_f32_32x32x16_f16(a, b, c, 0, 0, 0);
}

// ------------- prep: fused activation cvt (fp32->bf16) + weight transpose -------
__global__ __launch_bounds__(256) void prep(const float* __restrict__ q,
                                            const float* __restrict__ k,
                                            const float* __restrict__ v,
                                            const float* __restrict__ W0,
                                            const float* __restrict__ W1,
                                            const float* __restrict__ W2,
                                            bf16* __restrict__ actb,
                                            bf16* __restrict__ Wt) {
  __shared__ float t[64 * 69];
  const int z = blockIdx.y, tid = threadIdx.x;
  if (blockIdx.x < 4096) {
    const float* in = z == 0 ? q : (z == 1 ? k : v);
    bf16* o = actb + (size_t)z * 8388608;
    int i = blockIdx.x * 256 + tid;
    const float4* p = (const float4*)in;
    float4 a = p[i * 2], c = p[i * 2 + 1];
    bf16x8 r;
    r[0] = (bf16)a.x; r[1] = (bf16)a.y; r[2] = (bf16)a.z; r[3] = (bf16)a.w;
    r[4] = (bf16)c.x; r[5] = (bf16)c.y; r[6] = (bf16)c.z; r[7] = (bf16)c.w;
    ((bf16x8*)o)[i] = r;
  } else {
    const float* W = z == 0 ? W0 : (z == 1 ? W1 : W2);
    bf16* O = Wt + (size_t)z * (1024 * 1024);
    int lin = blockIdx.x - 4096;
    int k0 = (lin & 15) * 64, n0 = (lin >> 4) * 64;
    int r0 = tid >> 4, c0 = (tid & 15) * 4;
#pragma unroll
    for (int rr = 0; rr < 4; rr++) {
      int kk = r0 + rr * 16;
      float4 vv = *(const float4*)(W + (k0 + kk) * 1024 + n0 + c0);
      t[kk * 69 + c0 + 0] = vv.x; t[kk * 69 + c0 + 1] = vv.y;
      t[kk * 69 + c0 + 2] = vv.z; t[kk * 69 + c0 + 3] = vv.w;
    }
    __syncthreads();
#pragma unroll
    for (int rr = 0; rr < 4; rr++) {
      int n = r0 + rr * 16;
      bf16x4 o;
#pragma unroll
      for (int j = 0; j < 4; j++) o[j] = (bf16)t[(c0 + j) * 69 + n];
      *(bf16x4*)(O + (n0 + n) * 1024 + k0 + c0) = o;
    }
  }
}

// ---------------- batched projection GEMM, 128x128, m97 config ----------------
// z=0: qo = (A*Wq+bq)*SCQ bf16 [m][n]; z=1: ko = A*Wk+bk bf16 [m][n];
// z=2: vf = A*Wv+bv f16, 32x32x16-A-fragment order:
//      element (kv,d) of head hh: t32=(kv>>5)&3, u16=(kv>>4)&1, hl=(kv>>3)&1,
//      j=kv&7; db=(d>>5)&1; fi=(t32*2+u16)*2+db; lane=32*hl+(d&31);
//      off = (((b*16+hh)*16+kvb)*16+fi)*512 + lane*8 + j
__global__ __launch_bounds__(256, 3) void gemm_qkv(const bf16* __restrict__ Act,
                                                   const bf16* __restrict__ Wt,
                                                   const float* __restrict__ b0,
                                                   const float* __restrict__ b1,
                                                   const float* __restrict__ b2,
                                                   bf16* __restrict__ qo,
                                                   bf16* __restrict__ ko,
                                                   _Float16* __restrict__ vf) {
  __shared__ bf16 smem[16384];          // sA 8192 | sB 8192 (32 KB)
  bf16* sA = smem;
  bf16* sB = smem + 8192;
  const int tid = threadIdx.x;
  const int wave = tid >> 6, lane = tid & 63;
  const int quad = lane >> 4, l15 = lane & 15;
  const int z = blockIdx.z;
  const int m0 = blockIdx.x * 128, n0 = blockIdx.y * 128;
  const bf16* A = Act + (size_t)z * 8388608;
  const bf16* Bt = Wt + (size_t)z * 1048576;
  const float* bias = z == 0 ? b0 : (z == 1 ? b1 : b2);

  const bf16* ap[4]; const bf16* bp[4]; int lo[4];
#pragma unroll
  for (int i = 0; i < 4; i++) {
    int g = wave * 256 + i * 64 + lane;
    int row = g >> 3, jl = (g & 7) ^ (row & 7);
    ap[i] = A + (m0 + row) * 1024 + jl * 8;
    bp[i] = Bt + (n0 + row) * 1024 + jl * 8;
    lo[i] = (wave * 256 + i * 64) * 8;
  }
  const int wm = (wave & 1) * 64, wn = (wave >> 1) * 64;
  f32x4 acc[4][4] = {};

  for (int kt = 0; kt < 16; kt++) {
    const int ko_ = kt * 64;
#pragma unroll
    for (int i = 0; i < 4; i++) async16(ap[i] + ko_, sA + lo[i]);
#pragma unroll
    for (int i = 0; i < 4; i++) async16(bp[i] + ko_, sB + lo[i]);
    __syncthreads();
#pragma unroll
    for (int ks = 0; ks < 2; ks++) {
      bf16x8 af[4], bv[4];
#pragma unroll
      for (int mt = 0; mt < 4; mt++) {
        int m = wm + mt * 16 + l15;
        int ph = (ks * 4 + quad) ^ (m & 7);
        af[mt] = *(const bf16x8*)(sA + m * 64 + ph * 8);
      }
#pragma unroll
      for (int nt = 0; nt < 4; nt++) {
        int n = wn + nt * 16 + l15;
        int ph = (ks * 4 + quad) ^ (n & 7);
        bv[nt] = *(const bf16x8*)(sB + n * 64 + ph * 8);
      }
#pragma unroll
      for (int mt = 0; mt < 4; mt++)
#pragma unroll
        for (int nt = 0; nt < 4; nt++)
          acc[mt][nt] = mfma_bf16(af[mt], bv[nt], acc[mt][nt]);
    }
    __syncthreads();
  }

  if (z != 2) {
    bf16* O = z == 0 ? qo : ko;
    const float sc = z == 0 ? SCQ : 1.0f;
#pragma unroll
    for (int nt = 0; nt < 4; nt++) {
      int n = n0 + wn + nt * 16 + l15;
      float bc = bias[n];
#pragma unroll
      for (int mt = 0; mt < 4; mt++)
#pragma unroll
        for (int r = 0; r < 4; r++) {
          int m = m0 + wm + mt * 16 + quad * 4 + r;
          O[m * 1024 + n] = (bf16)((acc[mt][nt][r] + bc) * sc);
        }
    }
  } else {
    // 32x32x16 A-fragment-order stores (see header comment)
    const int b = m0 >> 11, s0 = m0 & 2047;
    const int kvb = s0 >> 7;
    const int mtg0 = (wave & 1) * 4;
    const int hl = quad >> 1, jb = (quad & 1) * 4;
#pragma unroll
    for (int nt = 0; nt < 4; nt++) {
      int n = n0 + wn + nt * 16;
      int hh = n >> 6, db = (n >> 5) & 1;
      int lanep = hl * 32 + (n & 31) + l15;
      float bc = bias[n + l15];
#pragma unroll
      for (int mt = 0; mt < 4; mt++) {
        int fi = (mtg0 + mt) * 2 + db;
        f16x4 pk;
#pragma unroll
        for (int r = 0; r < 4; r++) pk[r] = (_Float16)(acc[mt][nt][r] + bc);
        size_t off = ((((size_t)(b * 16 + hh) * 16 + kvb) * 16 + fi) * 512)
                     + lanep * 8 + jb;
        *(f16x4*)(vf + off) = pk;
      }
    }
  }
}

// ------------- flash attention, Q-tile 256, KV-64 double-buffered ------------
// Q pre-scaled bf16 [B,S,1024]; K bf16 [B,S,1024]; VF f16 32x32x16-frag order;
// Out fp32 [B,S,1024]. 4 waves x 64 q-rows (two 32-q column groups per wave):
// K-frag and V-frag ds_reads are shared across both groups; compute per
// barrier doubles; K/V global re-reads halve (16 -> 8 Q-blocks per panel).
// 64 KB LDS -> 2 blocks/CU (grid 512 = exactly co-resident).
__global__ __launch_bounds__(256, 2) void attn(const bf16* __restrict__ Q,
                                               const bf16* __restrict__ K,
                                               const _Float16* __restrict__ VF,
                                               float* __restrict__ Out) {
  __shared__ bf16 sQ[16384];                // 256 x 64 swizzled (32 KB)
  __shared__ bf16 sK0[4096], sK1[4096];     // 64 x 64 swizzled, dbuf (2x8 KB)
  __shared__ _Float16 sV0[4096], sV1[4096]; // 8 frags x 64 x 8, dbuf (2x8 KB)
  const int tid = threadIdx.x;
  const int wave = tid >> 6, lane = tid & 63;
  const int l31 = lane & 31, hl = lane >> 5;
  const int q0 = blockIdx.x * 256, hh = blockIdx.y, b = blockIdx.z;
  const bf16* Kbase = K + (size_t)(b * 2048) * 1024 + hh * 64;
  const _Float16* Vbase = VF + (size_t)(b * 16 + hh) * 131072;

  // per-thread staging addresses (2 K-loads + 2 V-loads per 64-row block)
  const int g0 = tid, g1 = 256 + tid;
  const int r0s = g0 >> 3, j0s = (g0 & 7) ^ (r0s & 7);
  const int r1s = g1 >> 3, j1s = (g1 & 7) ^ (r1s & 7);
  const bf16* kst0 = Kbase + (size_t)r0s * 1024 + j0s * 8;
  const bf16* kst1 = Kbase + (size_t)r1s * 1024 + j1s * 8;

  auto stageKV = [&](int t, bf16* sk, _Float16* sv) {
    async16(kst0 + (size_t)t * 65536, sk + g0 * 8);
    async16(kst1 + (size_t)t * 65536, sk + g1 * 8);
    async16(Vbase + t * 4096 + g0 * 8, sv + g0 * 8);
    async16(Vbase + t * 4096 + g1 * 8, sv + g1 * 8);
  };

  // prologue: Q (32 KB, 8 loads/thread) + K/V block 0
#pragma unroll
  for (int i = 0; i < 8; i++) {
    int g = i * 256 + tid;
    int row = g >> 3, jl = (g & 7) ^ (row & 7);
    async16(Q + (size_t)(b * 2048 + q0 + row) * 1024 + hh * 64 + jl * 8, sQ + g * 8);
  }
  stageKV(0, sK0, sV0);
  __syncthreads();

  // Q fragments: qc in {0,1} column groups; rows wave*64 + qc*32 + l31
  bf16x8 qf[2][4];
#pragma unroll
  for (int qc = 0; qc < 2; qc++) {
    int rowq = wave * 64 + qc * 32 + l31, rx = rowq & 7;
#pragma unroll
    for (int i = 0; i < 4; i++)
      qf[qc][i] = *(const bf16x8*)(sQ + rowq * 64 + ((2 * i + hl) ^ rx) * 8);
  }

  f32x16 oacc0[2] = {}, oacc1[2] = {};  // O^T per qc: [db]
  float ls0 = 0.f, ls1 = 0.f;

  // exp2+pack+permlane+PV for one 32q column group
  auto procP = [&](const f32x16& st, float& lsum, f32x16* oq, const f16x8* va) {
    unsigned int dw[8];
    float ps = 0.f;
#pragma unroll
    for (int s = 0; s < 4; s++) {
      float p0 = __builtin_amdgcn_exp2f(st[4 * s + 0]);
      float p1 = __builtin_amdgcn_exp2f(st[4 * s + 1]);
      float p2 = __builtin_amdgcn_exp2f(st[4 * s + 2]);
      float p3 = __builtin_amdgcn_exp2f(st[4 * s + 3]);
      ps += (p0 + p1) + (p2 + p3);
      dw[2 * s]     = __builtin_bit_cast(unsigned int,
                        __builtin_amdgcn_cvt_pkrtz(p0, p1));
      dw[2 * s + 1] = __builtin_bit_cast(unsigned int,
                        __builtin_amdgcn_cvt_pkrtz(p2, p3));
    }
    lsum += ps;
#pragma unroll
    for (int u = 0; u < 2; u++) {
      uint2v rA = __builtin_amdgcn_permlane32_swap(dw[4 * u + 0],
                                                   dw[4 * u + 2], false, false);
      uint2v rB = __builtin_amdgcn_permlane32_swap(dw[4 * u + 1],
                                                   dw[4 * u + 3], false, false);
      uint4v uu;
      uu[0] = rA[0]; uu[1] = rB[0]; uu[2] = rA[1]; uu[3] = rB[1];
      f16x8 pfrag = __builtin_bit_cast(f16x8, uu);
      __builtin_amdgcn_s_setprio(1);
#pragma unroll
      for (int db = 0; db < 2; db++)
        oq[db] = mfma32x16_f16(va[u * 2 + db], pfrag, oq[db]);
      __builtin_amdgcn_s_setprio(0);
    }
  };

  auto computeT = [&](const bf16* sk, const _Float16* sv) {
#pragma unroll
    for (int t32 = 0; t32 < 2; t32++) {
      // ---- S^T (32 kv x 2x32 q): A=K rows kv (shared), B=Q^T per group ----
      int rowk = t32 * 32 + l31, rx = rowk & 7;
      const bf16* kr = sk + rowk * 64;
      bf16x8 kf[4];
#pragma unroll
      for (int i = 0; i < 4; i++)
        kf[i] = *(const bf16x8*)(kr + ((2 * i + hl) ^ rx) * 8);
      f32x16 st0 = {}, st1 = {};
      __builtin_amdgcn_s_setprio(1);
#pragma unroll
      for (int i = 0; i < 4; i++) st0 = mfma32_bf16(kf[i], qf[0][i], st0);
#pragma unroll
      for (int i = 0; i < 4; i++) st1 = mfma32_bf16(kf[i], qf[1][i], st1);
      __builtin_amdgcn_s_setprio(0);
      // V fragments (shared across both q groups)
      f16x8 va[4];
#pragma unroll
      for (int u = 0; u < 2; u++)
#pragma unroll
        for (int db = 0; db < 2; db++)
          va[u * 2 + db] =
              *(const f16x8*)(sv + ((t32 * 4 + u * 2 + db) * 64 + lane) * 8);
      procP(st0, ls0, oacc0, va);
      procP(st1, ls1, oacc1, va);
    }
  };

  // 2-phase main loop over 32 KV-64 blocks (statically named buffers)
#pragma unroll 1
  for (int t = 0; t < 32; t += 2) {
    stageKV(t + 1, sK1, sV1);      // loads fly under compute
    computeT(sK0, sV0);
    __syncthreads();               // drains stage(t+1); buf0 readers done
    if (t + 2 < 32) stageKV(t + 2, sK0, sV0);
    computeT(sK1, sV1);
    __syncthreads();
  }

  // ---- epilogue: l = own-half + other-half, scale, store fp32 ----
  ls0 += __shfl_xor(ls0, 32);
  ls1 += __shfl_xor(ls1, 32);
#pragma unroll
  for (int qc = 0; qc < 2; qc++) {
    float inv = 1.f / (qc == 0 ? ls0 : ls1);
    const f32x16* oq = qc == 0 ? oacc0 : oacc1;
    int qrow = b * 2048 + q0 + wave * 64 + qc * 32 + l31;
    float* orow = Out + (size_t)qrow * 1024 + hh * 64;
#pragma unroll
    for (int db = 0; db < 2; db++)
#pragma unroll
      for (int rg = 0; rg < 4; rg++) {
        float4 v;
        v.x = oq[db][4 * rg + 0] * inv;
        v.y = oq[db][4 * rg + 1] * inv;
        v.z = oq[db][4 * rg + 2] * inv;
        v.w = oq[db][4 * rg + 3] * inv;
        *(float4*)(orow + db * 32 + rg * 8 + 4 * hl) = v;
      }
  }
}

extern "C" void kernel_launch(void* const* d_in, const int* in_sizes, int n_in,
                              void* d_out, int out_size, void* d_ws, size_t ws_size,
                              hipStream_t stream) {
  const float* key   = (const float*)d_in[0];
  const float* value = (const float*)d_in[1];
  const float* query = (const float*)d_in[2];
  const float* Wq = (const float*)d_in[3];
  const float* bq = (const float*)d_in[4];
  const float* Wk = (const float*)d_in[5];
  const float* bk = (const float*)d_in[6];
  const float* Wv = (const float*)d_in[7];
  const float* bv = (const float*)d_in[8];
  float* out = (float*)d_out;

  char* ws = (char*)d_ws;
  bf16* actb   = (bf16*)(ws);                       // 48 MB: [query|key|value] bf16
  bf16* wt     = (bf16*)(ws + 50331648);            // 6 MB: Wq^T,Wk^T,Wv^T
  bf16* qo     = (bf16*)(ws + 56623104);            // 16 MB (pre-scaled)
  bf16* ko     = (bf16*)(ws + 73400320);            // 16 MB
  _Float16* vf = (_Float16*)(ws + 90177536);        // 16 MB 32x32x16-frag order
  (void)in_sizes; (void)n_in; (void)out_size; (void)ws_size;

  prep<<<dim3(4352, 3), 256, 0, stream>>>(query, key, value, Wq, Wk, Wv, actb, wt);
  gemm_qkv<<<dim3(64, 8, 3), 256, 0, stream>>>(actb, wt, bq, bk, bv, qo, ko, vf);
  attn<<<dim3(8, 16, 4), 256, 0, stream>>>(qo, ko, vf, out);
}